// Round 6
// baseline (139.362 us; speedup 1.0000x reference)
//
#include <hip/hip_runtime.h>

#define LEAKY(v) ((v) > 0.0f ? (v) : 0.2f * (v))

// ---- K1: block 0 computes degree histogram in LDS (replaces memset+atomics);
//          blocks 1..255 zero agg1/agg2 and compute xw1 = x@W1 (feat 3..5) ----
__global__ __launch_bounds__(256) void k1_prep(
        const float* __restrict__ x, const int* __restrict__ col,
        const float* __restrict__ W1, float* __restrict__ deg,
        float* __restrict__ aggs /*agg1,agg2 contiguous*/,
        float* __restrict__ xw, int n, int E) {
    if (blockIdx.x == 0) {
        __shared__ float sdeg[1024];          // n <= 1024 (forced by fc1 shape)
        for (int i = threadIdx.x; i < n; i += 256) sdeg[i] = 0.0f;
        __syncthreads();
        for (int e = threadIdx.x; e < E; e += 256) atomicAdd(&sdeg[col[e]], 1.0f);
        __syncthreads();
        for (int i = threadIdx.x; i < n; i += 256) deg[i] = sdeg[i];
    } else {
        int tid = (blockIdx.x - 1) * 256 + threadIdx.x;
        int NT = (gridDim.x - 1) * 256;
        for (int i = tid; i < 2 * n * 32; i += NT) aggs[i] = 0.0f;
        for (int t = tid; t < n * 32; t += NT) {
            int j = t & 31, nn = t >> 5;
            xw[t] = x[nn*6+3] * W1[96+j]
                  + x[nn*6+4] * W1[128+j]
                  + x[nn*6+5] * W1[160+j];
        }
    }
}

// ---- scatter: agg[col] += xw[row] * rsqrt(deg[row]+1)*rsqrt(deg[col]+1),
//      incl. self-loops (e >= E); +1 folds the self-loop into the degree ----
__global__ void k_scatter(const float* __restrict__ xw, const float* __restrict__ deg,
                          const int* __restrict__ row, const int* __restrict__ col,
                          float* __restrict__ agg, int E, int n) {
    int tid = blockIdx.x * blockDim.x + threadIdx.x;
    int total = (E + n) * 32;
    if (tid >= total) return;
    int e = tid >> 5, j = tid & 31;
    int r, c; float nrm;
    if (e < E) {
        r = row[e]; c = col[e];
        nrm = (1.0f / sqrtf(deg[r] + 1.0f)) * (1.0f / sqrtf(deg[c] + 1.0f));
    } else {
        r = c = e - E;
        nrm = 1.0f / (deg[r] + 1.0f);
    }
    atomicAdd(&agg[c * 32 + j], xw[r * 32 + j] * nrm);
}

// ---- K3: xw = leaky(agg1 + b1) @ W2 ----
__global__ void k3_xw2(const float* __restrict__ agg1, const float* __restrict__ b1,
                       const float* __restrict__ W2, float* __restrict__ xw, int n) {
    int tid = blockIdx.x * blockDim.x + threadIdx.x;
    if (tid >= n * 32) return;
    int j = tid & 31, nn = tid >> 5;
    const float* a = agg1 + nn * 32;
    float s = 0.0f;
#pragma unroll
    for (int f = 0; f < 32; ++f) {
        float v = a[f] + b1[f];
        v = LEAKY(v);
        s += v * W2[f * 32 + j];
    }
    xw[tid] = s;
}

// ---- K5: fused conv1+conv2+conv3 -> c3 [3,123,29].
//      Block b = c3 row. Row-local chain: c3 row b <- c2 rows 2b..2b+3
//      <- c1 rows 4b..4b+9 <- h2 rows 8b..8b+21. LDS tiles, wide 123-block grid.
__global__ __launch_bounds__(256) void k5_conv123(
        const float* __restrict__ h2, const float* __restrict__ b2,
        const float* __restrict__ k1w, const float* __restrict__ kb1,
        const float* __restrict__ k2w, const float* __restrict__ kb2,
        const float* __restrict__ k3w, const float* __restrict__ kb3,
        float* __restrict__ c3) {
    __shared__ float lc1[10 * 3 * 31];   // [rl 0..9][co 0..2][col 0..30]
    __shared__ float lc2[4 * 6 * 30];    // [rl 0..3][co 0..5][col 0..29]
    const int b = blockIdx.x;            // c3 row, 0..122

    // stage 1: c1 rows 4b..4b+9
    for (int t = threadIdx.x; t < 10 * 3 * 31; t += 256) {
        int col_ = t % 31; int tt = t / 31; int co = tt % 3; int rl = tt / 3;
        int oh1 = 4 * b + rl;
        const float* ip = h2 + (2 * oh1) * 32 + col_;
        float v[4][2];
#pragma unroll
        for (int r = 0; r < 4; ++r)
#pragma unroll
            for (int cx = 0; cx < 2; ++cx) {
                float u = ip[r * 32 + cx] + b2[col_ + cx];
                v[r][cx] = LEAKY(u);
            }
        const float* wp = k1w + co * 6;
        float a0 = v[0][0]*wp[0] + v[0][1]*wp[1] + v[1][0]*wp[2]
                 + v[1][1]*wp[3] + v[2][0]*wp[4] + v[2][1]*wp[5];
        float a1 = v[1][0]*wp[0] + v[1][1]*wp[1] + v[2][0]*wp[2]
                 + v[2][1]*wp[3] + v[3][0]*wp[4] + v[3][1]*wp[5];
        float m = fmaxf(a0, a1) + kb1[co];
        lc1[t] = fmaxf(m, 0.0f);
    }
    __syncthreads();

    // stage 2: c2 rows 2b..2b+3 (local rl2, using lc1 local rows 2*rl2..2*rl2+3)
    for (int t = threadIdx.x; t < 4 * 6 * 30; t += 256) {
        int col_ = t % 30; int tt = t / 30; int co = tt % 6; int rl2 = tt / 6;
        float a0 = 0.0f, a1 = 0.0f;
#pragma unroll
        for (int ci = 0; ci < 3; ++ci) {
            const float* wp = k2w + (co * 3 + ci) * 6;
            const float* q0 = lc1 + ((2*rl2 + 0) * 3 + ci) * 31 + col_;
            const float* q1 = lc1 + ((2*rl2 + 1) * 3 + ci) * 31 + col_;
            const float* q2 = lc1 + ((2*rl2 + 2) * 3 + ci) * 31 + col_;
            const float* q3 = lc1 + ((2*rl2 + 3) * 3 + ci) * 31 + col_;
            a0 += q0[0]*wp[0] + q0[1]*wp[1] + q1[0]*wp[2] + q1[1]*wp[3] + q2[0]*wp[4] + q2[1]*wp[5];
            a1 += q1[0]*wp[0] + q1[1]*wp[1] + q2[0]*wp[2] + q2[1]*wp[3] + q3[0]*wp[4] + q3[1]*wp[5];
        }
        float m = fmaxf(a0, a1) + kb2[co];
        lc2[(rl2 * 6 + co) * 30 + col_] = fmaxf(m, 0.0f);
    }
    __syncthreads();

    // stage 3: c3 row b (3 co x 29 cols)
    for (int t = threadIdx.x; t < 3 * 29; t += 256) {
        int col_ = t % 29; int co = t / 29;
        float a0 = 0.0f, a1 = 0.0f;
#pragma unroll
        for (int ci = 0; ci < 6; ++ci) {
            const float* wp = k3w + (co * 6 + ci) * 6;
            const float* q0 = lc2 + (0 * 6 + ci) * 30 + col_;
            const float* q1 = lc2 + (1 * 6 + ci) * 30 + col_;
            const float* q2 = lc2 + (2 * 6 + ci) * 30 + col_;
            const float* q3 = lc2 + (3 * 6 + ci) * 30 + col_;
            a0 += q0[0]*wp[0] + q0[1]*wp[1] + q1[0]*wp[2] + q1[1]*wp[3] + q2[0]*wp[4] + q2[1]*wp[5];
            a1 += q1[0]*wp[0] + q1[1]*wp[1] + q2[0]*wp[2] + q2[1]*wp[3] + q3[0]*wp[4] + q3[1]*wp[5];
        }
        float m = fmaxf(a0, a1) + kb3[co];
        c3[(co * 123 + b) * 29 + col_] = fmaxf(m, 0.0f);
    }
}

// ---- K6: conv4 (redundant per block, tiny) into LDS, then FC1 rows ----
__global__ __launch_bounds__(256) void k6_conv4_fc1(
        const float* __restrict__ c3, const float* __restrict__ k4,
        const float* __restrict__ kb4, const float* __restrict__ fw1,
        const float* __restrict__ fb1, float* __restrict__ f1) {
    __shared__ __align__(16) float lc4[1680];
    const int Hin = 123, Win = 29, Wo = 28;
    float kb = kb4[0];
    for (int t0 = (int)threadIdx.x; t0 < 1680; t0 += 256) {
        int ow = t0 % Wo; int oh = t0 / Wo;
        float a0 = 0.0f, a1 = 0.0f;
#pragma unroll
        for (int ci = 0; ci < 3; ++ci) {
            const float* q = c3 + (ci * Hin + 2 * oh) * Win + ow;
            const float* wp = k4 + ci * 6;
            float r00 = q[0],     r01 = q[1];
            float r10 = q[Win],   r11 = q[Win+1];
            float r20 = q[2*Win], r21 = q[2*Win+1];
            float r30 = q[3*Win], r31 = q[3*Win+1];
            a0 += r00*wp[0] + r01*wp[1] + r10*wp[2] + r11*wp[3] + r20*wp[4] + r21*wp[5];
            a1 += r10*wp[0] + r11*wp[1] + r20*wp[2] + r21*wp[3] + r30*wp[4] + r31*wp[5];
        }
        float m = fmaxf(a0, a1) + kb;
        lc4[t0] = fmaxf(m, 0.0f);
    }
    __syncthreads();
    int wv = threadIdx.x >> 6, lane = threadIdx.x & 63;
    int o = blockIdx.x * 4 + wv;
    const float4* wr = (const float4*)(fw1 + (size_t)o * 1680);
    const float4* vv = (const float4*)lc4;
    float s = 0.0f;
    for (int i = lane; i < 420; i += 64) {
        float4 a = vv[i], ww = wr[i];
        s += a.x*ww.x + a.y*ww.y + a.z*ww.z + a.w*ww.w;
    }
#pragma unroll
    for (int off = 32; off > 0; off >>= 1) s += __shfl_down(s, off, 64);
    if (lane == 0) f1[o] = s + fb1[o];
}

// ---- FC 1024-in: one wave per row, float4 loads ----
__global__ __launch_bounds__(256) void k_fc1024(const float* __restrict__ v,
                                                const float* __restrict__ w,
                                                const float* __restrict__ b,
                                                float* __restrict__ out) {
    int wv = threadIdx.x >> 6, lane = threadIdx.x & 63;
    int o = blockIdx.x * 4 + wv;
    const float4* wr = (const float4*)(w + (size_t)o * 1024);
    const float4* vv = (const float4*)v;
    float s = 0.0f;
#pragma unroll
    for (int i = 0; i < 4; ++i) {
        float4 a = vv[lane + 64*i], ww = wr[lane + 64*i];
        s += a.x*ww.x + a.y*ww.y + a.z*ww.z + a.w*ww.w;
    }
#pragma unroll
    for (int off = 32; off > 0; off >>= 1) s += __shfl_down(s, off, 64);
    if (lane == 0) out[o] = s + b[o];
}

extern "C" void kernel_launch(void* const* d_in, const int* in_sizes, int n_in,
                              void* d_out, int out_size, void* d_ws, size_t ws_size,
                              hipStream_t stream) {
    const float* x   = (const float*)d_in[0];
    const int*   ei  = (const int*)d_in[1];
    const float* W1  = (const float*)d_in[2];
    const float* b1  = (const float*)d_in[3];
    const float* W2  = (const float*)d_in[4];
    const float* b2  = (const float*)d_in[5];
    const float* k1  = (const float*)d_in[6];
    const float* kb1 = (const float*)d_in[7];
    const float* k2  = (const float*)d_in[8];
    const float* kb2 = (const float*)d_in[9];
    const float* k3  = (const float*)d_in[10];
    const float* kb3 = (const float*)d_in[11];
    const float* k4  = (const float*)d_in[12];
    const float* kb4 = (const float*)d_in[13];
    const float* fw1 = (const float*)d_in[14];
    const float* fb1 = (const float*)d_in[15];
    const float* fw2 = (const float*)d_in[16];
    const float* fb2 = (const float*)d_in[17];
    const float* fw3 = (const float*)d_in[18];
    const float* fb3 = (const float*)d_in[19];

    int n = in_sizes[0] / 6;       // 1000
    int E = in_sizes[1] / 2;       // 8000
    const int* row = ei;
    const int* col = ei + E;

    float* ws   = (float*)d_ws;
    float* deg  = ws;              // 1024
    float* agg1 = ws + 1024;       // 32000 (agg1+agg2 contiguous for K1 zeroing)
    float* agg2 = agg1 + 32000;    // 32000
    float* xw   = agg2 + 32000;    // 32000
    float* c3   = xw + 32000;      // 3*123*29 = 10701
    float* f1   = c3 + 10704;      // 1024 (16B aligned)
    float* f2   = f1 + 1024;       // 1024

    const int B = 256;

    k1_prep<<<256, B, 0, stream>>>(x, col, W1, deg, agg1, xw, n, E);
    int st = (E + n) * 32;
    k_scatter<<<(st + B - 1) / B, B, 0, stream>>>(xw, deg, row, col, agg1, E, n);
    k3_xw2<<<(n * 32 + B - 1) / B, B, 0, stream>>>(agg1, b1, W2, xw, n);
    k_scatter<<<(st + B - 1) / B, B, 0, stream>>>(xw, deg, row, col, agg2, E, n);
    k5_conv123<<<123, B, 0, stream>>>(agg2, b2, k1, kb1, k2, kb2, k3, kb3, c3);
    k6_conv4_fc1<<<256, B, 0, stream>>>(c3, k4, kb4, fw1, fb1, f1);
    k_fc1024<<<256, B, 0, stream>>>(f1, fw2, fb2, f2);
    k_fc1024<<<16, B, 0, stream>>>(f2, fw3, fb3, (float*)d_out);
}

// Round 7
// 134.470 us; speedup vs baseline: 1.0364x; 1.0364x over previous
//
#include <hip/hip_runtime.h>

#define LEAKY(v) ((v) > 0.0f ? (v) : 0.2f * (v))

// ---- K1: zero agg1/agg2, degree atomics (edges only; self-loop folded as +1),
//          xw1 = x@W1 (features 3..5 only; 0..2 zeroed by forward) ----
__global__ void k1_prep(const float* __restrict__ x, const int* __restrict__ col,
                        const float* __restrict__ W1, float* __restrict__ deg,
                        float* __restrict__ aggs /*agg1,agg2 contiguous*/,
                        float* __restrict__ xw, int n, int E) {
    int tid = blockIdx.x * blockDim.x + threadIdx.x;
    int NT = gridDim.x * blockDim.x;
    for (int i = tid; i < 2 * n * 32; i += NT) aggs[i] = 0.0f;
    for (int e = tid; e < E; e += NT) atomicAdd(&deg[col[e]], 1.0f);
    for (int t = tid; t < n * 32; t += NT) {
        int j = t & 31, nn = t >> 5;
        xw[t] = x[nn*6+3] * W1[96+j]
              + x[nn*6+4] * W1[128+j]
              + x[nn*6+5] * W1[160+j];
    }
}

// ---- scatter: agg[col] += xw[row] * rsqrt(deg[row]+1)*rsqrt(deg[col]+1),
//      incl. self-loops (e >= E) ----
__global__ void k_scatter(const float* __restrict__ xw, const float* __restrict__ deg,
                          const int* __restrict__ row, const int* __restrict__ col,
                          float* __restrict__ agg, int E, int n) {
    int tid = blockIdx.x * blockDim.x + threadIdx.x;
    int total = (E + n) * 32;
    if (tid >= total) return;
    int e = tid >> 5, j = tid & 31;
    int r, c; float nrm;
    if (e < E) {
        r = row[e]; c = col[e];
        nrm = (1.0f / sqrtf(deg[r] + 1.0f)) * (1.0f / sqrtf(deg[c] + 1.0f));
    } else {
        r = c = e - E;
        nrm = 1.0f / (deg[r] + 1.0f);
    }
    atomicAdd(&agg[c * 32 + j], xw[r * 32 + j] * nrm);
}

// ---- K3: xw = leaky(agg1 + b1) @ W2 ----
__global__ void k3_xw2(const float* __restrict__ agg1, const float* __restrict__ b1,
                       const float* __restrict__ W2, float* __restrict__ xw, int n) {
    int tid = blockIdx.x * blockDim.x + threadIdx.x;
    if (tid >= n * 32) return;
    int j = tid & 31, nn = tid >> 5;
    const float* a = agg1 + nn * 32;
    float s = 0.0f;
#pragma unroll
    for (int f = 0; f < 32; ++f) {
        float v = a[f] + b1[f];
        v = LEAKY(v);
        s += v * W2[f * 32 + j];
    }
    xw[tid] = s;
}

// ---- K5: conv1 (+b2, leaky on input) + relu + pool -> c1 [3,499,31] ----
__global__ void k5_conv1(const float* __restrict__ h2, const float* __restrict__ b2,
                         const float* __restrict__ w, const float* __restrict__ bias,
                         float* __restrict__ out) {
    const int Hp = 499, Wo = 31, total = 3 * Hp * Wo;
    int t0 = blockIdx.x * blockDim.x + threadIdx.x;
    if (t0 >= total) return;
    int ow = t0 % Wo; int t = t0 / Wo; int oh = t % Hp; int co = t / Hp;
    const float* ip = h2 + (2 * oh) * 32 + ow;
    float vals[4][2];
#pragma unroll
    for (int r = 0; r < 4; ++r)
#pragma unroll
        for (int cx = 0; cx < 2; ++cx) {
            float v = ip[r * 32 + cx] + b2[ow + cx];
            vals[r][cx] = LEAKY(v);
        }
    const float* wp = w + co * 6;
    float a0 = vals[0][0]*wp[0] + vals[0][1]*wp[1] + vals[1][0]*wp[2]
             + vals[1][1]*wp[3] + vals[2][0]*wp[4] + vals[2][1]*wp[5];
    float a1 = vals[1][0]*wp[0] + vals[1][1]*wp[1] + vals[2][0]*wp[2]
             + vals[2][1]*wp[3] + vals[3][0]*wp[4] + vals[3][1]*wp[5];
    float m = fmaxf(a0, a1) + bias[co];
    out[t0] = fmaxf(m, 0.0f);
}

// ---- K6: conv2 -> c2 [6,248,30] ----
__global__ void k6_conv2(const float* __restrict__ in, const float* __restrict__ w,
                         const float* __restrict__ bias, float* __restrict__ out) {
    const int CI = 3, Hin = 499, Win = 31, Hp = 248, Wo = 30, total = 6 * Hp * Wo;
    int t0 = blockIdx.x * blockDim.x + threadIdx.x;
    if (t0 >= total) return;
    int ow = t0 % Wo; int t = t0 / Wo; int oh = t % Hp; int co = t / Hp;
    float a0 = 0.0f, a1 = 0.0f;
#pragma unroll
    for (int ci = 0; ci < CI; ++ci) {
        const float* q = in + (ci * Hin + 2 * oh) * Win + ow;
        const float* wp = w + (co * CI + ci) * 6;
        float r00 = q[0],     r01 = q[1];
        float r10 = q[Win],   r11 = q[Win+1];
        float r20 = q[2*Win], r21 = q[2*Win+1];
        float r30 = q[3*Win], r31 = q[3*Win+1];
        a0 += r00*wp[0] + r01*wp[1] + r10*wp[2] + r11*wp[3] + r20*wp[4] + r21*wp[5];
        a1 += r10*wp[0] + r11*wp[1] + r20*wp[2] + r21*wp[3] + r30*wp[4] + r31*wp[5];
    }
    float m = fmaxf(a0, a1) + bias[co];
    out[t0] = fmaxf(m, 0.0f);
}

// ---- K7: conv3 -> c3 [3,123,29]; wide grid (42 blocks), one thread/output ----
__global__ void k7_conv3(const float* __restrict__ in, const float* __restrict__ w,
                         const float* __restrict__ bias, float* __restrict__ out) {
    const int CI = 6, Hin = 248, Win = 30, Hp = 123, Wo = 29, total = 3 * Hp * Wo;
    int t0 = blockIdx.x * blockDim.x + threadIdx.x;
    if (t0 >= total) return;
    int ow = t0 % Wo; int t = t0 / Wo; int oh = t % Hp; int co = t / Hp;
    float a0 = 0.0f, a1 = 0.0f;
#pragma unroll
    for (int ci = 0; ci < CI; ++ci) {
        const float* q = in + (ci * Hin + 2 * oh) * Win + ow;
        const float* wp = w + (co * CI + ci) * 6;
        float r00 = q[0],     r01 = q[1];
        float r10 = q[Win],   r11 = q[Win+1];
        float r20 = q[2*Win], r21 = q[2*Win+1];
        float r30 = q[3*Win], r31 = q[3*Win+1];
        a0 += r00*wp[0] + r01*wp[1] + r10*wp[2] + r11*wp[3] + r20*wp[4] + r21*wp[5];
        a1 += r10*wp[0] + r11*wp[1] + r20*wp[2] + r21*wp[3] + r30*wp[4] + r31*wp[5];
    }
    float m = fmaxf(a0, a1) + bias[co];
    out[t0] = fmaxf(m, 0.0f);
}

// ---- K8: conv4 (redundant per block, tiny: 48 loads + 36 FMA per output)
//          into LDS, then FC1 rows o = blockIdx*4 + wave ----
__global__ __launch_bounds__(256) void k8_conv4_fc1(
        const float* __restrict__ c3, const float* __restrict__ k4,
        const float* __restrict__ kb4, const float* __restrict__ fw1,
        const float* __restrict__ fb1, float* __restrict__ f1) {
    __shared__ __align__(16) float lc4[1680];
    const int Hin = 123, Win = 29, Wo = 28;
    float kb = kb4[0];
    for (int t0 = (int)threadIdx.x; t0 < 1680; t0 += 256) {
        int ow = t0 % Wo; int oh = t0 / Wo;
        float a0 = 0.0f, a1 = 0.0f;
#pragma unroll
        for (int ci = 0; ci < 3; ++ci) {
            const float* q = c3 + (ci * Hin + 2 * oh) * Win + ow;
            const float* wp = k4 + ci * 6;
            float r00 = q[0],     r01 = q[1];
            float r10 = q[Win],   r11 = q[Win+1];
            float r20 = q[2*Win], r21 = q[2*Win+1];
            float r30 = q[3*Win], r31 = q[3*Win+1];
            a0 += r00*wp[0] + r01*wp[1] + r10*wp[2] + r11*wp[3] + r20*wp[4] + r21*wp[5];
            a1 += r10*wp[0] + r11*wp[1] + r20*wp[2] + r21*wp[3] + r30*wp[4] + r31*wp[5];
        }
        float m = fmaxf(a0, a1) + kb;
        lc4[t0] = fmaxf(m, 0.0f);
    }
    __syncthreads();
    int wv = threadIdx.x >> 6, lane = threadIdx.x & 63;
    int o = blockIdx.x * 4 + wv;
    const float4* wr = (const float4*)(fw1 + (size_t)o * 1680);
    const float4* vv = (const float4*)lc4;
    float s = 0.0f;
    for (int i = lane; i < 420; i += 64) {
        float4 a = vv[i], ww = wr[i];
        s += a.x*ww.x + a.y*ww.y + a.z*ww.z + a.w*ww.w;
    }
#pragma unroll
    for (int off = 32; off > 0; off >>= 1) s += __shfl_down(s, off, 64);
    if (lane == 0) f1[o] = s + fb1[o];
}

// ---- FC 1024-in: one wave per row, float4 loads ----
__global__ __launch_bounds__(256) void k_fc1024(const float* __restrict__ v,
                                                const float* __restrict__ w,
                                                const float* __restrict__ b,
                                                float* __restrict__ out) {
    int wv = threadIdx.x >> 6, lane = threadIdx.x & 63;
    int o = blockIdx.x * 4 + wv;
    const float4* wr = (const float4*)(w + (size_t)o * 1024);
    const float4* vv = (const float4*)v;
    float s = 0.0f;
#pragma unroll
    for (int i = 0; i < 4; ++i) {
        float4 a = vv[lane + 64*i], ww = wr[lane + 64*i];
        s += a.x*ww.x + a.y*ww.y + a.z*ww.z + a.w*ww.w;
    }
#pragma unroll
    for (int off = 32; off > 0; off >>= 1) s += __shfl_down(s, off, 64);
    if (lane == 0) out[o] = s + b[o];
}

extern "C" void kernel_launch(void* const* d_in, const int* in_sizes, int n_in,
                              void* d_out, int out_size, void* d_ws, size_t ws_size,
                              hipStream_t stream) {
    const float* x   = (const float*)d_in[0];
    const int*   ei  = (const int*)d_in[1];
    const float* W1  = (const float*)d_in[2];
    const float* b1  = (const float*)d_in[3];
    const float* W2  = (const float*)d_in[4];
    const float* b2  = (const float*)d_in[5];
    const float* k1  = (const float*)d_in[6];
    const float* kb1 = (const float*)d_in[7];
    const float* k2  = (const float*)d_in[8];
    const float* kb2 = (const float*)d_in[9];
    const float* k3  = (const float*)d_in[10];
    const float* kb3 = (const float*)d_in[11];
    const float* k4  = (const float*)d_in[12];
    const float* kb4 = (const float*)d_in[13];
    const float* fw1 = (const float*)d_in[14];
    const float* fb1 = (const float*)d_in[15];
    const float* fw2 = (const float*)d_in[16];
    const float* fb2 = (const float*)d_in[17];
    const float* fw3 = (const float*)d_in[18];
    const float* fb3 = (const float*)d_in[19];

    int n = in_sizes[0] / 6;       // 1000
    int E = in_sizes[1] / 2;       // 8000
    const int* row = ei;
    const int* col = ei + E;

    float* ws   = (float*)d_ws;
    float* deg  = ws;              // 1024
    float* agg1 = ws + 1024;       // 32000 (agg1+agg2 contiguous for K1 zeroing)
    float* agg2 = agg1 + 32000;    // 32000
    float* xw   = agg2 + 32000;    // 32000
    float* c1   = xw + 32000;      // 3*499*31 = 46407
    float* c2   = c1 + 46407;      // 6*248*30 = 44640
    float* c3   = c2 + 44640;      // 3*123*29 = 10701
    float* f1   = c3 + 10704;      // 1024 (16B aligned)
    float* f2   = f1 + 1024;       // 1024

    const int B = 256;

    hipMemsetAsync(deg, 0, n * sizeof(float), stream);
    k1_prep<<<256, B, 0, stream>>>(x, col, W1, deg, agg1, xw, n, E);
    int st = (E + n) * 32;
    k_scatter<<<(st + B - 1) / B, B, 0, stream>>>(xw, deg, row, col, agg1, E, n);
    k3_xw2<<<(n * 32 + B - 1) / B, B, 0, stream>>>(agg1, b1, W2, xw, n);
    k_scatter<<<(st + B - 1) / B, B, 0, stream>>>(xw, deg, row, col, agg2, E, n);
    k5_conv1<<<(3 * 499 * 31 + B - 1) / B, B, 0, stream>>>(agg2, b2, k1, kb1, c1);
    k6_conv2<<<(6 * 248 * 30 + B - 1) / B, B, 0, stream>>>(c1, k2, kb2, c2);
    k7_conv3<<<(3 * 123 * 29 + B - 1) / B, B, 0, stream>>>(c2, k3, kb3, c3);
    k8_conv4_fc1<<<256, B, 0, stream>>>(c3, k4, kb4, fw1, fb1, f1);
    k_fc1024<<<256, B, 0, stream>>>(f1, fw2, fb2, f2);
    k_fc1024<<<16, B, 0, stream>>>(f2, fw3, fb3, (float*)d_out);
}